// Round 7
// baseline (280.558 us; speedup 1.0000x reference)
//
#include <hip/hip_runtime.h>
#include <cstddef>
#include <cmath>

// ---------------------------------------------------------------------------
// SWGAT layer:
//   z = h @ W_fc.T                       [N,128]
//   e = leaky_relu(a1[src] + a2[dst]);  e==0 -> -1000
//   segment softmax over dst, out[w] = sum alpha * z[src]
// R7: gemm stuck ~55us with ALL pipes <10% across R4-R6 -> suspect VMEM
//     instruction issue (64 scalar 2B z-stores/lane; C/D layout forbids
//     packing). Swap MFMA operands (A=W, B=h): D rows become z-COLUMNS, so
//     each lane holds 4 consecutive cols of one row -> packed half4 8B
//     stores, 16 instrs/lane (4x fewer). a1/a2 reduce: 2 shfl steps (quads).
//     h-frag loads + wh swizzle unchanged. hist vectorized int4.
// ---------------------------------------------------------------------------

#define IN_DIM  256
#define OUT_DIM 128

typedef _Float16 half2_t __attribute__((ext_vector_type(2)));
typedef _Float16 half4_t __attribute__((ext_vector_type(4)));
typedef _Float16 half8_t __attribute__((ext_vector_type(8)));
typedef float    f32x4   __attribute__((ext_vector_type(4)));

// --- K0: convert W_fc fp32 -> f16, swizzled granule layout ------------------
// granule g = n*32 + (kb ^ (n&7)) holds wfc[n][kb*8 .. kb*8+7]
__global__ __launch_bounds__(256) void wconv_kernel(const float* __restrict__ wfc,
                                                    _Float16* __restrict__ wh) {
    int idx = blockIdx.x * 256 + threadIdx.x;   // 0..4095 (n*32+kb)
    int n  = idx >> 5;
    int kb = idx & 31;
    const float* p = wfc + (size_t)n * IN_DIM + kb * 8;
    float4 v0 = *(const float4*)p;
    float4 v1 = *(const float4*)(p + 4);
    half8_t hv = {(_Float16)v0.x, (_Float16)v0.y, (_Float16)v0.z, (_Float16)v0.w,
                  (_Float16)v1.x, (_Float16)v1.y, (_Float16)v1.z, (_Float16)v1.w};
    *(half8_t*)&wh[(size_t)(n * 32 + (kb ^ (n & 7))) * 8] = hv;
}

// --- K1: z = h @ W_fc.T via mfma_f32_16x16x32_f16 (A=W, B=h) ---------------
// block: 512 thr = 8 waves, tile 256 rows. Wave w owns rows {w*16..+15} and
// {128+w*16..+15} (l15 = row-in-tile via B-operand n-index). D layout:
// col(n)=l15 -> z-row; row(m)=quad*4+r -> z-col => lane packs 4 cols/store.
__global__ __launch_bounds__(512, 4) void gemm_kernel(const float* __restrict__ h,
                                                      const _Float16* __restrict__ wh,
                                                      const float* __restrict__ wattn,
                                                      _Float16* __restrict__ zh,
                                                      float* __restrict__ a1,
                                                      float* __restrict__ a2, int M) {
    __shared__ _Float16 Ws[IN_DIM * OUT_DIM];   // 64 KB, pre-swizzled granules

    const int t    = threadIdx.x;
    const int lane = t & 63;
    const int w    = t >> 6;          // 0..7
    const int quad = lane >> 4;       // 0..3
    const int l15  = lane & 15;
    const int m0   = blockIdx.x * 256;

    // ---- stage W: linear 16B copies of pre-swizzled f16 W ----
#pragma unroll
    for (int i = 0; i < 8; ++i) {
        int idx = t + i * 512;        // granule 0..4095
        *(half8_t*)&Ws[(size_t)idx * 8] = *(const half8_t*)&wh[(size_t)idx * 8];
    }
    __syncthreads();   // the ONLY block-wide barrier

    // lane's two h rows (B-operand: n = l15); clamped, OOB never stored
    const int g0 = (m0 + w * 16 + l15 < M) ? (m0 + w * 16 + l15) : (M - 1);
    const int g1 = (m0 + 128 + w * 16 + l15 < M) ? (m0 + 128 + w * 16 + l15) : (M - 1);
    const float* hrow0 = h + (size_t)g0 * IN_DIM;
    const float* hrow1 = h + (size_t)g1 * IN_DIM;

    f32x4 acc[2][8] = {};   // [row-set][col-tile ni]

#pragma unroll
    for (int kc = 0; kc < 8; ++kc) {
        // B-frags (h) straight from global: 8 fp32 = 32 B contiguous per lane
        float4 u0 = *(const float4*)(hrow0 + kc * 32 + quad * 8);
        float4 u1 = *(const float4*)(hrow0 + kc * 32 + quad * 8 + 4);
        float4 v0 = *(const float4*)(hrow1 + kc * 32 + quad * 8);
        float4 v1 = *(const float4*)(hrow1 + kc * 32 + quad * 8 + 4);
        half8_t b0 = {(_Float16)u0.x, (_Float16)u0.y, (_Float16)u0.z, (_Float16)u0.w,
                      (_Float16)u1.x, (_Float16)u1.y, (_Float16)u1.z, (_Float16)u1.w};
        half8_t b1 = {(_Float16)v0.x, (_Float16)v0.y, (_Float16)v0.z, (_Float16)v0.w,
                      (_Float16)v1.x, (_Float16)v1.y, (_Float16)v1.z, (_Float16)v1.w};
#pragma unroll
        for (int ni = 0; ni < 8; ++ni) {
            int n = ni * 16 + l15;                  // W row = z col
            int g = (kc * 4 + quad) ^ (n & 7);
            half8_t a = *(const half8_t*)&Ws[(size_t)(n * 32 + g) * 8];  // A-frag
            acc[0][ni] = __builtin_amdgcn_mfma_f32_16x16x32_f16(a, b0, acc[0][ni], 0, 0, 0);
            acc[1][ni] = __builtin_amdgcn_mfma_f32_16x16x32_f16(a, b1, acc[1][ni], 0, 0, 0);
        }
    }

    // ---- epilogue: lane owns z[row = m0+s*128+w*16+l15][cols ni*16+quad*4+r]
#pragma unroll
    for (int s = 0; s < 2; ++s) {
        int row = m0 + s * 128 + w * 16 + l15;
        float p1 = 0.f, p2 = 0.f;
#pragma unroll
        for (int ni = 0; ni < 8; ++ni) {
            float4 w1q = *(const float4*)(wattn + ni * 16 + quad * 4);
            float4 w2q = *(const float4*)(wattn + OUT_DIM + ni * 16 + quad * 4);
            p1 += acc[s][ni][0] * w1q.x + acc[s][ni][1] * w1q.y
                + acc[s][ni][2] * w1q.z + acc[s][ni][3] * w1q.w;
            p2 += acc[s][ni][0] * w2q.x + acc[s][ni][1] * w2q.y
                + acc[s][ni][2] * w2q.z + acc[s][ni][3] * w2q.w;
            if (row < M) {
                half4_t pk = {(_Float16)acc[s][ni][0], (_Float16)acc[s][ni][1],
                              (_Float16)acc[s][ni][2], (_Float16)acc[s][ni][3]};
                *(half4_t*)&zh[(size_t)row * OUT_DIM + ni * 16 + quad * 4] = pk;
            }
        }
        // reduce over quads (lanes l15, +16, +32, +48 share the row)
        p1 += __shfl_xor(p1, 16);  p1 += __shfl_xor(p1, 32);
        p2 += __shfl_xor(p2, 16);  p2 += __shfl_xor(p2, 32);
        if (lane < 16 && row < M) { a1[row] = p1; a2[row] = p2; }
    }
}

// --- K4: histogram of dst (4 edges/thread, int4) ----------------------------
__global__ void hist_kernel(const int* __restrict__ dst, int* __restrict__ cnt, int E) {
    int i = (blockIdx.x * 256 + threadIdx.x) * 4;
    if (i + 4 <= E) {
        int4 d = *(const int4*)(dst + i);
        atomicAdd(&cnt[d.x], 1);
        atomicAdd(&cnt[d.y], 1);
        atomicAdd(&cnt[d.z], 1);
        atomicAdd(&cnt[d.w], 1);
    } else {
        for (int j = i; j < E; ++j) atomicAdd(&cnt[dst[j]], 1);
    }
}

// --- K5a: per-block reduce of cnt -> bsum[196] ------------------------------
__global__ __launch_bounds__(256) void scan_reduce_kernel(const int* __restrict__ cnt,
                                                          int* __restrict__ bsum, int NW) {
    __shared__ int sm[4];
    const int t = threadIdx.x;
    const int i = blockIdx.x * 256 + t;
    int v = (i < NW) ? cnt[i] : 0;
#pragma unroll
    for (int o = 32; o; o >>= 1) v += __shfl_xor(v, o);
    if ((t & 63) == 0) sm[t >> 6] = v;
    __syncthreads();
    if (t == 0) bsum[blockIdx.x] = sm[0] + sm[1] + sm[2] + sm[3];
}

// --- K5b: exclusive scan of <=256 block partials (one block) ----------------
__global__ __launch_bounds__(256) void scan_partials_kernel(const int* __restrict__ bsum,
                                                            int* __restrict__ bpre, int nb,
                                                            int* __restrict__ off, int NW, int E) {
    __shared__ int sm[256];
    const int t = threadIdx.x;
    int v = (t < nb) ? bsum[t] : 0;
    sm[t] = v;
    __syncthreads();
    for (int d = 1; d < 256; d <<= 1) {
        int u = (t >= d) ? sm[t - d] : 0;
        __syncthreads();
        sm[t] += u;
        __syncthreads();
    }
    if (t < nb) bpre[t] = sm[t] - v;   // exclusive prefix of block t
    if (t == 0) off[NW] = E;
}

// --- K5c: block-local exclusive scan + block offset -> off, cur -------------
__global__ __launch_bounds__(256) void scan_final_kernel(const int* __restrict__ cnt,
                                                         const int* __restrict__ bpre,
                                                         int* __restrict__ off,
                                                         int* __restrict__ cur, int NW) {
    __shared__ int sm[256];
    const int t = threadIdx.x;
    const int i = blockIdx.x * 256 + t;
    int v = (i < NW) ? cnt[i] : 0;
    sm[t] = v;
    __syncthreads();
    for (int d = 1; d < 256; d <<= 1) {
        int u = (t >= d) ? sm[t - d] : 0;
        __syncthreads();
        sm[t] += u;
        __syncthreads();
    }
    int ex = sm[t] - v + bpre[blockIdx.x];
    if (i < NW) { off[i] = ex; cur[i] = ex; }
}

// --- K6: scatter edges into CSR order, computing masked leaky scores --------
__global__ void scatter_kernel(const int* __restrict__ src, const int* __restrict__ dst,
                               const float* __restrict__ a1, const float* __restrict__ a2,
                               int* __restrict__ cur, int* __restrict__ esrc,
                               float* __restrict__ evals, int E) {
    int i = blockIdx.x * 256 + threadIdx.x;
    if (i >= E) return;
    int s = src[i];
    int d = dst[i];
    float x = a1[s] + a2[d];
    float e = x > 0.f ? x : 0.01f * x;          // leaky_relu(0.01)
    if (e == 0.f) e = -1000.f;                  // DGL zero-mask emulation
    int pos = atomicAdd(&cur[d], 1);
    esrc[pos]  = s;
    evals[pos] = e;
}

// --- K7: per-dst softmax + weighted aggregation (one wave per dst) ----------
// Fast path (deg<=64): evals/esrc register-resident, weights broadcast by
// shfl, z-row (f16, 256B) loads unrolled x4 for memory-level parallelism.
__global__ __launch_bounds__(256) void agg_kernel(const _Float16* __restrict__ zh,
                                                  const int* __restrict__ off,
                                                  const int* __restrict__ esrc,
                                                  const float* __restrict__ evals,
                                                  float* __restrict__ out, int NW) {
    const int lane = threadIdx.x & 63;
    const int w = blockIdx.x * 4 + (threadIdx.x >> 6);
    if (w >= NW) return;
    const int beg = off[w];
    const int end = off[w + 1];
    const int cnt = end - beg;

    float2 acc = make_float2(0.f, 0.f);

    if (cnt <= 64) {
        float ev = (lane < cnt) ? evals[beg + lane] : -INFINITY;
        int   se = (lane < cnt) ? esrc[beg + lane] : 0;
        float mx = ev;
#pragma unroll
        for (int o = 32; o; o >>= 1) mx = fmaxf(mx, __shfl_xor(mx, o));
        float ex = (lane < cnt) ? __expf(ev - mx) : 0.f;
        float s = ex;
#pragma unroll
        for (int o = 32; o; o >>= 1) s += __shfl_xor(s, o);
        ex *= (cnt > 0) ? (1.0f / s) : 0.f;      // per-lane alpha

        int j = 0;
        for (; j + 4 <= cnt; j += 4) {
            int   s0 = __shfl(se, j),     s1 = __shfl(se, j + 1);
            int   s2 = __shfl(se, j + 2), s3 = __shfl(se, j + 3);
            float w0 = __shfl(ex, j),     w1 = __shfl(ex, j + 1);
            float w2 = __shfl(ex, j + 2), w3 = __shfl(ex, j + 3);
            half2_t z0 = *(const half2_t*)(zh + (size_t)s0 * OUT_DIM + lane * 2);
            half2_t z1 = *(const half2_t*)(zh + (size_t)s1 * OUT_DIM + lane * 2);
            half2_t z2 = *(const half2_t*)(zh + (size_t)s2 * OUT_DIM + lane * 2);
            half2_t z3 = *(const half2_t*)(zh + (size_t)s3 * OUT_DIM + lane * 2);
            acc.x += w0 * (float)z0[0] + w1 * (float)z1[0] + w2 * (float)z2[0] + w3 * (float)z3[0];
            acc.y += w0 * (float)z0[1] + w1 * (float)z1[1] + w2 * (float)z2[1] + w3 * (float)z3[1];
        }
        for (; j < cnt; ++j) {
            int   sj = __shfl(se, j);
            float wj = __shfl(ex, j);
            half2_t zj = *(const half2_t*)(zh + (size_t)sj * OUT_DIM + lane * 2);
            acc.x += wj * (float)zj[0];
            acc.y += wj * (float)zj[1];
        }
    } else {
        // rare fallback: degree > 64
        float mx = -INFINITY;
        for (int j = beg + lane; j < end; j += 64) mx = fmaxf(mx, evals[j]);
#pragma unroll
        for (int o = 32; o; o >>= 1) mx = fmaxf(mx, __shfl_xor(mx, o));
        float s = 0.f;
        for (int j = beg + lane; j < end; j += 64) s += __expf(evals[j] - mx);
#pragma unroll
        for (int o = 32; o; o >>= 1) s += __shfl_xor(s, o);
        const float inv = 1.0f / s;
        for (int j = beg; j < end; ++j) {
            int   sidx = esrc[j];
            float wgt  = __expf(evals[j] - mx) * inv;
            half2_t zr = *(const half2_t*)(zh + (size_t)sidx * OUT_DIM + lane * 2);
            acc.x += wgt * (float)zr[0];
            acc.y += wgt * (float)zr[1];
        }
    }
    ((float2*)(out + (size_t)w * OUT_DIM))[lane] = acc;   // always written (zeros if empty)
}

// ---------------------------------------------------------------------------
extern "C" void kernel_launch(void* const* d_in, const int* in_sizes, int n_in,
                              void* d_out, int out_size, void* d_ws, size_t ws_size,
                              hipStream_t stream) {
    const float* h     = (const float*)d_in[0];
    const int*   src   = (const int*)d_in[1];
    const int*   dst   = (const int*)d_in[2];
    const float* wfc   = (const float*)d_in[3];
    const float* wattn = (const float*)d_in[4];
    float*       out   = (float*)d_out;

    const int N  = in_sizes[0] / IN_DIM;   // 100000
    const int E  = in_sizes[1];            // 500000
    const int NW = out_size / OUT_DIM;     // 50000
    const int nb = (NW + 255) / 256;       // 196 scan blocks (<=256 required)

    // workspace layout
    _Float16* zh = (_Float16*)d_ws;               // N*128 f16
    _Float16* wh = zh + (size_t)N * OUT_DIM;      // 256*128 f16 (swizzled)
    float* a1    = (float*)(wh + IN_DIM * OUT_DIM);  // N
    float* a2    = a1 + N;                        // N
    int*   cnt   = (int*)(a2 + N);                // NW
    int*   off   = cnt + NW;                      // NW+1
    int*   cur   = off + NW + 1;                  // NW
    int*   esrc  = cur + NW;                      // E
    float* evals = (float*)(esrc + E);            // E
    int*   bsum  = (int*)(evals + E);             // nb
    int*   bpre  = bsum + nb;                     // nb

    wconv_kernel<<<16, 256, 0, stream>>>(wfc, wh);
    gemm_kernel<<<(N + 255) / 256, 512, 0, stream>>>(h, wh, wattn, zh, a1, a2, N);
    hipMemsetAsync(cnt, 0, (size_t)NW * sizeof(int), stream);
    hist_kernel<<<(E / 4 + 255) / 256, 256, 0, stream>>>(dst, cnt, E);
    scan_reduce_kernel<<<nb, 256, 0, stream>>>(cnt, bsum, NW);
    scan_partials_kernel<<<1, 256, 0, stream>>>(bsum, bpre, nb, off, NW, E);
    scan_final_kernel<<<nb, 256, 0, stream>>>(cnt, bpre, off, cur, NW);
    scatter_kernel<<<(E + 255) / 256, 256, 0, stream>>>(src, dst, a1, a2, cur, esrc, evals, E);
    agg_kernel<<<(NW + 3) / 4, 256, 0, stream>>>(zh, off, esrc, evals, out, NW);
}

// Round 8
// 269.007 us; speedup vs baseline: 1.0429x; 1.0429x over previous
//
#include <hip/hip_runtime.h>
#include <cstddef>
#include <cmath>

// ---------------------------------------------------------------------------
// SWGAT layer:
//   z = h @ W_fc.T                       [N,128]
//   e = leaky_relu(a1[src] + a2[dst]);  e==0 -> -1000
//   segment softmax over dst, out[w] = sum alpha * z[src]
// R8: gemm pinned at 55-67us across three structures with ALL pipes idle ->
//     unhidden load latency (only ~2-3 loads in flight/wave, no prefetch
//     across barriers). New gemm = software-pipelined: A(h) double-buffered
//     in LDS, next-next tile's global loads issued while current tile's
//     MFMAs run; one barrier/interval; B(W) LDS-resident pre-swizzled.
//     256thr/128row blocks (782 blocks, 80KB LDS -> 2 blocks/CU).
// ---------------------------------------------------------------------------

#define IN_DIM  256
#define OUT_DIM 128

typedef _Float16 half2_t __attribute__((ext_vector_type(2)));
typedef _Float16 half4_t __attribute__((ext_vector_type(4)));
typedef _Float16 half8_t __attribute__((ext_vector_type(8)));
typedef float    f32x4   __attribute__((ext_vector_type(4)));

// --- K0: convert W_fc fp32 -> f16, swizzled granule layout ------------------
// granule g = n*32 + (kb ^ (n&7)) holds wfc[n][kb*8 .. kb*8+7]
__global__ __launch_bounds__(256) void wconv_kernel(const float* __restrict__ wfc,
                                                    _Float16* __restrict__ wh) {
    int idx = blockIdx.x * 256 + threadIdx.x;   // 0..4095 (n*32+kb)
    int n  = idx >> 5;
    int kb = idx & 31;
    const float* p = wfc + (size_t)n * IN_DIM + kb * 8;
    float4 v0 = *(const float4*)p;
    float4 v1 = *(const float4*)(p + 4);
    half8_t hv = {(_Float16)v0.x, (_Float16)v0.y, (_Float16)v0.z, (_Float16)v0.w,
                  (_Float16)v1.x, (_Float16)v1.y, (_Float16)v1.z, (_Float16)v1.w};
    *(half8_t*)&wh[(size_t)(n * 32 + (kb ^ (n & 7))) * 8] = hv;
}

// --- K1: z = h @ W_fc.T via mfma_f32_16x16x32_f16 (A=W, B=h), pipelined -----
// block: 256 thr = 4 waves, tile 128 rows x 128 cols. Wave w owns rows
// w*32 + {0..15, 16..31} (two row-sets), all 128 cols.
// Hs planar layout: plane q (k=q*8..q*8+7), row r -> granule (q*128+r)*8 f16.
// b-frag read = 16 consecutive rows x 16B contiguous -> conflict-free.
__global__ __launch_bounds__(256, 2) void gemm_kernel(const float* __restrict__ h,
                                                      const _Float16* __restrict__ wh,
                                                      const float* __restrict__ wattn,
                                                      _Float16* __restrict__ zh,
                                                      float* __restrict__ a1,
                                                      float* __restrict__ a2, int M) {
    __shared__ _Float16 Ws[IN_DIM * OUT_DIM];    // 64 KB, pre-swizzled granules
    __shared__ _Float16 Hs[2][4 * 128 * 8];      // 2 x 8 KB, planar granules

    const int t    = threadIdx.x;
    const int lane = t & 63;
    const int w    = t >> 6;          // 0..3
    const int quad = lane >> 4;       // 0..3
    const int l15  = lane & 15;
    const int m0   = blockIdx.x * 128;

    // staging role: thread t handles row=t>>1, k-half=(t&1)*16 of each tile
    const int srow = t >> 1;
    const int skh  = t & 1;
    const int sgr  = (m0 + srow < M) ? (m0 + srow) : (M - 1);   // clamped
    const float* hrow = h + (size_t)sgr * IN_DIM + skh * 16;

    // ---- stage Ws: linear 16B copies of pre-swizzled f16 W ----
#pragma unroll
    for (int i = 0; i < 16; ++i) {
        int idx = t + i * 256;        // granule 0..4095
        *(half8_t*)&Ws[(size_t)idx * 8] = *(const half8_t*)&wh[(size_t)idx * 8];
    }

    float4 v0, v1, v2, v3;            // prefetch regs (16 fp32 = 64B of one row)
#define LOADV(kc)  do { const float* p = hrow + (kc) * 32;                      \
                        v0 = *(const float4*)p;      v1 = *(const float4*)(p+4); \
                        v2 = *(const float4*)(p+8);  v3 = *(const float4*)(p+12);} while(0)
#define WRITEV(buf) do {                                                        \
        half8_t g0 = {(_Float16)v0.x,(_Float16)v0.y,(_Float16)v0.z,(_Float16)v0.w, \
                      (_Float16)v1.x,(_Float16)v1.y,(_Float16)v1.z,(_Float16)v1.w}; \
        half8_t g1 = {(_Float16)v2.x,(_Float16)v2.y,(_Float16)v2.z,(_Float16)v2.w, \
                      (_Float16)v3.x,(_Float16)v3.y,(_Float16)v3.z,(_Float16)v3.w}; \
        *(half8_t*)&Hs[buf][((skh * 2    ) * 128 + srow) * 8] = g0;             \
        *(half8_t*)&Hs[buf][((skh * 2 + 1) * 128 + srow) * 8] = g1; } while(0)

    LOADV(0);
    WRITEV(0);
    LOADV(1);
    __syncthreads();                  // Ws + Hs[0] ready

    f32x4 acc[2][8] = {};             // [row-set][col-tile ni]

#pragma unroll
    for (int kc = 0; kc < 8; ++kc) {
        const int buf = kc & 1;
        // b-frags (h rows) from planar LDS: plane=quad, rows w*32+s*16+l15
        half8_t b0 = *(const half8_t*)&Hs[buf][(quad * 128 + w * 32 + l15) * 8];
        half8_t b1 = *(const half8_t*)&Hs[buf][(quad * 128 + w * 32 + 16 + l15) * 8];
#pragma unroll
        for (int ni = 0; ni < 8; ++ni) {
            int n = ni * 16 + l15;                  // W row = z col
            int g = (kc * 4 + quad) ^ (n & 7);
            half8_t a = *(const half8_t*)&Ws[(size_t)(n * 32 + g) * 8];
            acc[0][ni] = __builtin_amdgcn_mfma_f32_16x16x32_f16(a, b0, acc[0][ni], 0, 0, 0);
            acc[1][ni] = __builtin_amdgcn_mfma_f32_16x16x32_f16(a, b1, acc[1][ni], 0, 0, 0);
        }
        if (kc < 7) {
            WRITEV(!buf);             // v holds tile kc+1
            if (kc < 6) LOADV(kc + 2);  // in flight during next compute
            __syncthreads();          // Hs[!buf] ready; all reads of buf done
        }
    }
#undef LOADV
#undef WRITEV

    // ---- epilogue: lane owns z[row=m0+w*32+s*16+l15][cols ni*16+quad*4+r] --
#pragma unroll
    for (int s = 0; s < 2; ++s) {
        int row = m0 + w * 32 + s * 16 + l15;
        float p1 = 0.f, p2 = 0.f;
#pragma unroll
        for (int ni = 0; ni < 8; ++ni) {
            float4 w1q = *(const float4*)(wattn + ni * 16 + quad * 4);
            float4 w2q = *(const float4*)(wattn + OUT_DIM + ni * 16 + quad * 4);
            p1 += acc[s][ni][0] * w1q.x + acc[s][ni][1] * w1q.y
                + acc[s][ni][2] * w1q.z + acc[s][ni][3] * w1q.w;
            p2 += acc[s][ni][0] * w2q.x + acc[s][ni][1] * w2q.y
                + acc[s][ni][2] * w2q.z + acc[s][ni][3] * w2q.w;
            if (row < M) {
                half4_t pk = {(_Float16)acc[s][ni][0], (_Float16)acc[s][ni][1],
                              (_Float16)acc[s][ni][2], (_Float16)acc[s][ni][3]};
                *(half4_t*)&zh[(size_t)row * OUT_DIM + ni * 16 + quad * 4] = pk;
            }
        }
        // reduce over quads (lanes l15, +16, +32, +48 share the row)
        p1 += __shfl_xor(p1, 16);  p1 += __shfl_xor(p1, 32);
        p2 += __shfl_xor(p2, 16);  p2 += __shfl_xor(p2, 32);
        if (lane < 16 && row < M) { a1[row] = p1; a2[row] = p2; }
    }
}

// --- K4: histogram of dst (4 edges/thread, int4) ----------------------------
__global__ void hist_kernel(const int* __restrict__ dst, int* __restrict__ cnt, int E) {
    int i = (blockIdx.x * 256 + threadIdx.x) * 4;
    if (i + 4 <= E) {
        int4 d = *(const int4*)(dst + i);
        atomicAdd(&cnt[d.x], 1);
        atomicAdd(&cnt[d.y], 1);
        atomicAdd(&cnt[d.z], 1);
        atomicAdd(&cnt[d.w], 1);
    } else {
        for (int j = i; j < E; ++j) atomicAdd(&cnt[dst[j]], 1);
    }
}

// --- K5a: per-block reduce of cnt -> bsum[196] ------------------------------
__global__ __launch_bounds__(256) void scan_reduce_kernel(const int* __restrict__ cnt,
                                                          int* __restrict__ bsum, int NW) {
    __shared__ int sm[4];
    const int t = threadIdx.x;
    const int i = blockIdx.x * 256 + t;
    int v = (i < NW) ? cnt[i] : 0;
#pragma unroll
    for (int o = 32; o; o >>= 1) v += __shfl_xor(v, o);
    if ((t & 63) == 0) sm[t >> 6] = v;
    __syncthreads();
    if (t == 0) bsum[blockIdx.x] = sm[0] + sm[1] + sm[2] + sm[3];
}

// --- K5b: exclusive scan of <=256 block partials (one block) ----------------
__global__ __launch_bounds__(256) void scan_partials_kernel(const int* __restrict__ bsum,
                                                            int* __restrict__ bpre, int nb,
                                                            int* __restrict__ off, int NW, int E) {
    __shared__ int sm[256];
    const int t = threadIdx.x;
    int v = (t < nb) ? bsum[t] : 0;
    sm[t] = v;
    __syncthreads();
    for (int d = 1; d < 256; d <<= 1) {
        int u = (t >= d) ? sm[t - d] : 0;
        __syncthreads();
        sm[t] += u;
        __syncthreads();
    }
    if (t < nb) bpre[t] = sm[t] - v;   // exclusive prefix of block t
    if (t == 0) off[NW] = E;
}

// --- K5c: block-local exclusive scan + block offset -> off, cur -------------
__global__ __launch_bounds__(256) void scan_final_kernel(const int* __restrict__ cnt,
                                                         const int* __restrict__ bpre,
                                                         int* __restrict__ off,
                                                         int* __restrict__ cur, int NW) {
    __shared__ int sm[256];
    const int t = threadIdx.x;
    const int i = blockIdx.x * 256 + t;
    int v = (i < NW) ? cnt[i] : 0;
    sm[t] = v;
    __syncthreads();
    for (int d = 1; d < 256; d <<= 1) {
        int u = (t >= d) ? sm[t - d] : 0;
        __syncthreads();
        sm[t] += u;
        __syncthreads();
    }
    int ex = sm[t] - v + bpre[blockIdx.x];
    if (i < NW) { off[i] = ex; cur[i] = ex; }
}

// --- K6: scatter edges into CSR order, computing masked leaky scores --------
__global__ void scatter_kernel(const int* __restrict__ src, const int* __restrict__ dst,
                               const float* __restrict__ a1, const float* __restrict__ a2,
                               int* __restrict__ cur, int* __restrict__ esrc,
                               float* __restrict__ evals, int E) {
    int i = blockIdx.x * 256 + threadIdx.x;
    if (i >= E) return;
    int s = src[i];
    int d = dst[i];
    float x = a1[s] + a2[d];
    float e = x > 0.f ? x : 0.01f * x;          // leaky_relu(0.01)
    if (e == 0.f) e = -1000.f;                  // DGL zero-mask emulation
    int pos = atomicAdd(&cur[d], 1);
    esrc[pos]  = s;
    evals[pos] = e;
}

// --- K7: per-dst softmax + weighted aggregation (one wave per dst) ----------
// Fast path (deg<=64): evals/esrc register-resident, weights broadcast by
// shfl, z-row (f16, 256B) loads unrolled x4 for memory-level parallelism.
__global__ __launch_bounds__(256) void agg_kernel(const _Float16* __restrict__ zh,
                                                  const int* __restrict__ off,
                                                  const int* __restrict__ esrc,
                                                  const float* __restrict__ evals,
                                                  float* __restrict__ out, int NW) {
    const int lane = threadIdx.x & 63;
    const int w = blockIdx.x * 4 + (threadIdx.x >> 6);
    if (w >= NW) return;
    const int beg = off[w];
    const int end = off[w + 1];
    const int cnt = end - beg;

    float2 acc = make_float2(0.f, 0.f);

    if (cnt <= 64) {
        float ev = (lane < cnt) ? evals[beg + lane] : -INFINITY;
        int   se = (lane < cnt) ? esrc[beg + lane] : 0;
        float mx = ev;
#pragma unroll
        for (int o = 32; o; o >>= 1) mx = fmaxf(mx, __shfl_xor(mx, o));
        float ex = (lane < cnt) ? __expf(ev - mx) : 0.f;
        float s = ex;
#pragma unroll
        for (int o = 32; o; o >>= 1) s += __shfl_xor(s, o);
        ex *= (cnt > 0) ? (1.0f / s) : 0.f;      // per-lane alpha

        int j = 0;
        for (; j + 4 <= cnt; j += 4) {
            int   s0 = __shfl(se, j),     s1 = __shfl(se, j + 1);
            int   s2 = __shfl(se, j + 2), s3 = __shfl(se, j + 3);
            float w0 = __shfl(ex, j),     w1 = __shfl(ex, j + 1);
            float w2 = __shfl(ex, j + 2), w3 = __shfl(ex, j + 3);
            half2_t z0 = *(const half2_t*)(zh + (size_t)s0 * OUT_DIM + lane * 2);
            half2_t z1 = *(const half2_t*)(zh + (size_t)s1 * OUT_DIM + lane * 2);
            half2_t z2 = *(const half2_t*)(zh + (size_t)s2 * OUT_DIM + lane * 2);
            half2_t z3 = *(const half2_t*)(zh + (size_t)s3 * OUT_DIM + lane * 2);
            acc.x += w0 * (float)z0[0] + w1 * (float)z1[0] + w2 * (float)z2[0] + w3 * (float)z3[0];
            acc.y += w0 * (float)z0[1] + w1 * (float)z1[1] + w2 * (float)z2[1] + w3 * (float)z3[1];
        }
        for (; j < cnt; ++j) {
            int   sj = __shfl(se, j);
            float wj = __shfl(ex, j);
            half2_t zj = *(const half2_t*)(zh + (size_t)sj * OUT_DIM + lane * 2);
            acc.x += wj * (float)zj[0];
            acc.y += wj * (float)zj[1];
        }
    } else {
        // rare fallback: degree > 64
        float mx = -INFINITY;
        for (int j = beg + lane; j < end; j += 64) mx = fmaxf(mx, evals[j]);
#pragma unroll
        for (int o = 32; o; o >>= 1) mx = fmaxf(mx, __shfl_xor(mx, o));
        float s = 0.f;
        for (int j = beg + lane; j < end; j += 64) s += __expf(evals[j] - mx);
#pragma unroll
        for (int o = 32; o; o >>= 1) s += __shfl_xor(s, o);
        const float inv = 1.0f / s;
        for (int j = beg; j < end; ++j) {
            int   sidx = esrc[j];
            float wgt  = __expf(evals[j] - mx) * inv;
            half2_t zr = *(const half2_t*)(zh + (size_t)sidx * OUT_DIM + lane * 2);
            acc.x += wgt * (float)zr[0];
            acc.y += wgt * (float)zr[1];
        }
    }
    ((float2*)(out + (size_t)w * OUT_DIM))[lane] = acc;   // always written (zeros if empty)
}

// ---------------------------------------------------------------------------
extern "C" void kernel_launch(void* const* d_in, const int* in_sizes, int n_in,
                              void* d_out, int out_size, void* d_ws, size_t ws_size,
                              hipStream_t stream) {
    const float* h     = (const float*)d_in[0];
    const int*   src   = (const int*)d_in[1];
    const int*   dst   = (const int*)d_in[2];
    const float* wfc   = (const float*)d_in[3];
    const float* wattn = (const float*)d_in[4];
    float*       out   = (float*)d_out;

    const int N  = in_sizes[0] / IN_DIM;   // 100000
    const int E  = in_sizes[1];            // 500000
    const int NW = out_size / OUT_DIM;     // 50000
    const int nb = (NW + 255) / 256;       // 196 scan blocks (<=256 required)

    // workspace layout
    _Float16* zh = (_Float16*)d_ws;               // N*128 f16
    _Float16* wh = zh + (size_t)N * OUT_DIM;      // 256*128 f16 (swizzled)
    float* a1    = (float*)(wh + IN_DIM * OUT_DIM);  // N
    float* a2    = a1 + N;                        // N
    int*   cnt   = (int*)(a2 + N);                // NW
    int*   off   = cnt + NW;                      // NW+1
    int*   cur   = off + NW + 1;                  // NW
    int*   esrc  = cur + NW;                      // E
    float* evals = (float*)(esrc + E);            // E
    int*   bsum  = (int*)(evals + E);             // nb
    int*   bpre  = bsum + nb;                     // nb

    wconv_kernel<<<16, 256, 0, stream>>>(wfc, wh);
    gemm_kernel<<<(N + 127) / 128, 256, 0, stream>>>(h, wh, wattn, zh, a1, a2, N);
    hipMemsetAsync(cnt, 0, (size_t)NW * sizeof(int), stream);
    hist_kernel<<<(E / 4 + 255) / 256, 256, 0, stream>>>(dst, cnt, E);
    scan_reduce_kernel<<<nb, 256, 0, stream>>>(cnt, bsum, NW);
    scan_partials_kernel<<<1, 256, 0, stream>>>(bsum, bpre, nb, off, NW, E);
    scan_final_kernel<<<nb, 256, 0, stream>>>(cnt, bpre, off, cur, NW);
    scatter_kernel<<<(E + 255) / 256, 256, 0, stream>>>(src, dst, a1, a2, cur, esrc, evals, E);
    agg_kernel<<<(NW + 3) / 4, 256, 0, stream>>>(zh, off, esrc, evals, out, NW);
}